// Round 1
// baseline (184.941 us; speedup 1.0000x reference)
//
#include <hip/hip_runtime.h>
#include <math.h>

#define BLOCK 256
#define GRID  2048

// tanh(x) = 1 - 2/(exp(2x)+1)  via v_exp_f32 + v_rcp_f32 (approx, ~1e-7 rel)
__device__ __forceinline__ float fast_tanh(float x) {
    float e = __expf(2.0f * x);
    float r = __builtin_amdgcn_rcpf(e + 1.0f);
    return 1.0f - 2.0f * r;
}

__device__ __forceinline__ float stepf(float x) {
    return (fast_tanh(5.0f * x) + 1.0f) * 0.5f;
}

// shared-weight layout offsets (floats)
#define O_ETW1 0      // 48
#define O_ETB1 48     // 16
#define O_ETW2 64     // 256
#define O_ETB2 320    // 16
#define O_ETW3 336    // 16
#define O_QW1  352    // 32
#define O_QB1  384    // 16
#define O_QW2  400    // 256
#define O_QB2  656    // 16
#define O_QW3  672    // 16
#define O_ETB3 688    // 1
#define O_QB3  689    // 1
#define SW_TOTAL 690

__global__ __launch_bounds__(BLOCK) void exphydro_rhs_kernel(
    const float* __restrict__ t, const float* __restrict__ S_snow,
    const float* __restrict__ S_water,
    const float* __restrict__ precp_s, const float* __restrict__ temp_s,
    const float* __restrict__ lday_s,
    const float* __restrict__ etW1, const float* __restrict__ etb1,
    const float* __restrict__ etW2, const float* __restrict__ etb2,
    const float* __restrict__ etW3, const float* __restrict__ etb3,
    const float* __restrict__ qW1, const float* __restrict__ qb1,
    const float* __restrict__ qW2, const float* __restrict__ qb2,
    const float* __restrict__ qW3, const float* __restrict__ qb3,
    const float* __restrict__ pDf, const float* __restrict__ pTmax,
    const float* __restrict__ pTmin,
    float* __restrict__ out, int N, int T)
{
    __shared__ float sW[SW_TOTAL];
    const int tid = threadIdx.x;

    // cooperative weight staging (once per block)
    for (int k = tid; k < 48;  k += BLOCK) sW[O_ETW1 + k] = etW1[k];
    for (int k = tid; k < 16;  k += BLOCK) sW[O_ETB1 + k] = etb1[k];
    for (int k = tid; k < 256; k += BLOCK) sW[O_ETW2 + k] = etW2[k];
    for (int k = tid; k < 16;  k += BLOCK) sW[O_ETB2 + k] = etb2[k];
    for (int k = tid; k < 16;  k += BLOCK) sW[O_ETW3 + k] = etW3[k];
    for (int k = tid; k < 32;  k += BLOCK) sW[O_QW1  + k] = qW1[k];
    for (int k = tid; k < 16;  k += BLOCK) sW[O_QB1  + k] = qb1[k];
    for (int k = tid; k < 256; k += BLOCK) sW[O_QW2  + k] = qW2[k];
    for (int k = tid; k < 16;  k += BLOCK) sW[O_QB2  + k] = qb2[k];
    for (int k = tid; k < 16;  k += BLOCK) sW[O_QW3  + k] = qW3[k];
    if (tid == 0) { sW[O_ETB3] = etb3[0]; sW[O_QB3] = qb3[0]; }
    __syncthreads();

    const float Df   = pDf[0];
    const float Tmax = pTmax[0];
    const float Tmin = pTmin[0];
    const float tmaxf = (float)(T - 1);
    const int   imax  = T - 2;

    const int stride = gridDim.x * blockDim.x;
    for (int i = blockIdx.x * BLOCK + tid; i < N; i += stride) {
        float tv    = t[i];
        float ssnow = S_snow[i];
        float swat  = S_water[i];

        // linear interp on uniform grid ts = 0..T-1 (clamped like jnp.interp)
        float tc = fminf(fmaxf(tv, 0.0f), tmaxf);
        int i0 = (int)tc;
        i0 = (i0 > imax) ? imax : i0;
        float fr = tc - (float)i0;
        float p0 = precp_s[i0], p1 = precp_s[i0 + 1];
        float precp = fmaf(fr, p1 - p0, p0);
        float e0 = temp_s[i0], e1 = temp_s[i0 + 1];
        float temp = fmaf(fr, e1 - e0, e0);
        float l0 = lday_s[i0], l1 = lday_s[i0 + 1];
        float lday = fmaf(fr, l1 - l0, l0);

        float a[16], h[16];

        // ---------------- ET MLP: x = [ssnow, swat, temp] ----------------
        #pragma unroll
        for (int j = 0; j < 16; j++) a[j] = sW[O_ETB1 + j];
        #pragma unroll
        for (int j = 0; j < 16; j++) a[j] = fmaf(ssnow, sW[O_ETW1 + j], a[j]);
        #pragma unroll
        for (int j = 0; j < 16; j++) a[j] = fmaf(swat,  sW[O_ETW1 + 16 + j], a[j]);
        #pragma unroll
        for (int j = 0; j < 16; j++) a[j] = fmaf(temp,  sW[O_ETW1 + 32 + j], a[j]);
        #pragma unroll
        for (int j = 0; j < 16; j++) h[j] = fast_tanh(a[j]);

        #pragma unroll
        for (int j = 0; j < 16; j++) a[j] = sW[O_ETB2 + j];
        #pragma unroll
        for (int k = 0; k < 16; k++) {
            float hk = h[k];
            #pragma unroll
            for (int j = 0; j < 16; j++)
                a[j] = fmaf(hk, sW[O_ETW2 + k * 16 + j], a[j]);
        }
        #pragma unroll
        for (int j = 0; j < 16; j++) h[j] = fast_tanh(a[j]);

        float ET = sW[O_ETB3];
        #pragma unroll
        for (int j = 0; j < 16; j++) ET = fmaf(h[j], sW[O_ETW3 + j], ET);

        // ---------------- Q MLP: x = [swat, precp] ----------------
        #pragma unroll
        for (int j = 0; j < 16; j++) a[j] = sW[O_QB1 + j];
        #pragma unroll
        for (int j = 0; j < 16; j++) a[j] = fmaf(swat,  sW[O_QW1 + j], a[j]);
        #pragma unroll
        for (int j = 0; j < 16; j++) a[j] = fmaf(precp, sW[O_QW1 + 16 + j], a[j]);
        #pragma unroll
        for (int j = 0; j < 16; j++) h[j] = fast_tanh(a[j]);

        #pragma unroll
        for (int j = 0; j < 16; j++) a[j] = sW[O_QB2 + j];
        #pragma unroll
        for (int k = 0; k < 16; k++) {
            float hk = h[k];
            #pragma unroll
            for (int j = 0; j < 16; j++)
                a[j] = fmaf(hk, sW[O_QW2 + k * 16 + j], a[j]);
        }
        #pragma unroll
        for (int j = 0; j < 16; j++) h[j] = fast_tanh(a[j]);

        float Q = sW[O_QB3];
        #pragma unroll
        for (int j = 0; j < 16; j++) Q = fmaf(h[j], sW[O_QW3 + j], Q);

        // ---------------- bucket physics ----------------
        float dT   = temp - Tmax;
        float melt = stepf(dT) * stepf(ssnow) * fminf(ssnow, Df * dT);
        float Ps   = stepf(Tmin - temp) * precp;
        float Pr   = stepf(temp - Tmin) * precp;
        float sw01 = stepf(swat);

        float dS1 = Ps - melt;
        float dS2 = Pr + melt - sw01 * lday * __expf(ET) - sw01 * __expf(Q);

        out[i]     = dS1;
        out[N + i] = dS2;
    }
}

extern "C" void kernel_launch(void* const* d_in, const int* in_sizes, int n_in,
                              void* d_out, int out_size, void* d_ws, size_t ws_size,
                              hipStream_t stream) {
    const float* t        = (const float*)d_in[0];
    const float* S_snow   = (const float*)d_in[1];
    const float* S_water  = (const float*)d_in[2];
    // d_in[3] = ts (uniform grid, only need T)
    const float* precp_s  = (const float*)d_in[4];
    const float* temp_s   = (const float*)d_in[5];
    const float* lday_s   = (const float*)d_in[6];
    const float* etW1     = (const float*)d_in[7];
    const float* etb1     = (const float*)d_in[8];
    const float* etW2     = (const float*)d_in[9];
    const float* etb2     = (const float*)d_in[10];
    const float* etW3     = (const float*)d_in[11];
    const float* etb3     = (const float*)d_in[12];
    const float* qW1      = (const float*)d_in[13];
    const float* qb1      = (const float*)d_in[14];
    const float* qW2      = (const float*)d_in[15];
    const float* qb2      = (const float*)d_in[16];
    const float* qW3      = (const float*)d_in[17];
    const float* qb3      = (const float*)d_in[18];
    const float* pDf      = (const float*)d_in[19];
    const float* pTmax    = (const float*)d_in[20];
    const float* pTmin    = (const float*)d_in[21];

    int N = in_sizes[0];
    int T = in_sizes[3];
    float* out = (float*)d_out;

    exphydro_rhs_kernel<<<GRID, BLOCK, 0, stream>>>(
        t, S_snow, S_water, precp_s, temp_s, lday_s,
        etW1, etb1, etW2, etb2, etW3, etb3,
        qW1, qb1, qW2, qb2, qW3, qb3,
        pDf, pTmax, pTmin, out, N, T);
}

// Round 2
// 74.574 us; speedup vs baseline: 2.4800x; 2.4800x over previous
//
#include <hip/hip_runtime.h>
#include <math.h>

#define BLOCK 256

// tanh(x) = 1 - 2/(exp(2x)+1)  via v_exp_f32 + v_rcp_f32 (~1e-7 rel)
__device__ __forceinline__ float fast_tanh(float x) {
    float e = __expf(2.0f * x);
    float r = __builtin_amdgcn_rcpf(e + 1.0f);
    return 1.0f - 2.0f * r;
}

__device__ __forceinline__ float stepf(float x) {
    return (fast_tanh(5.0f * x) + 1.0f) * 0.5f;
}

// Pack the 3 forcing series into an interleaved float4 table in d_ws so the
// per-point interp needs 2×16B gathers (same cache line) instead of 6×4B.
__global__ __launch_bounds__(BLOCK) void pack_forcings_kernel(
    const float* __restrict__ precp_s, const float* __restrict__ temp_s,
    const float* __restrict__ lday_s, float4* __restrict__ F, int T)
{
    int i = blockIdx.x * BLOCK + threadIdx.x;
    if (i < T) F[i] = make_float4(precp_s[i], temp_s[i], lday_s[i], 0.0f);
}

__global__ __launch_bounds__(BLOCK, 4) void exphydro_rhs_kernel(
    const float* __restrict__ t, const float* __restrict__ S_snow,
    const float* __restrict__ S_water,
    const float4* __restrict__ F,            // packed forcings [T]
    const float* __restrict__ etW1, const float* __restrict__ etb1,
    const float* __restrict__ etW2, const float* __restrict__ etb2,
    const float* __restrict__ etW3, const float* __restrict__ etb3,
    const float* __restrict__ qW1, const float* __restrict__ qb1,
    const float* __restrict__ qW2, const float* __restrict__ qb2,
    const float* __restrict__ qW3, const float* __restrict__ qb3,
    const float* __restrict__ pDf, const float* __restrict__ pTmax,
    const float* __restrict__ pTmin,
    float* __restrict__ out, int N, int T)
{
    const int i = blockIdx.x * BLOCK + threadIdx.x;
    if (i >= N) return;

    const float Df   = pDf[0];     // uniform -> s_load
    const float Tmax = pTmax[0];
    const float Tmin = pTmin[0];
    const float tmaxf = (float)(T - 1);
    const int   imax  = T - 2;

    float tv    = t[i];
    float ssnow = S_snow[i];
    float swat  = S_water[i];

    // linear interp on uniform grid ts = 0..T-1 (clamped like jnp.interp)
    float tc = fminf(fmaxf(tv, 0.0f), tmaxf);
    int i0 = (int)tc;
    i0 = (i0 > imax) ? imax : i0;
    float fr = tc - (float)i0;
    float4 f0 = F[i0];
    float4 f1 = F[i0 + 1];
    float precp = fmaf(fr, f1.x - f0.x, f0.x);
    float temp  = fmaf(fr, f1.y - f0.y, f0.y);
    float lday  = fmaf(fr, f1.z - f0.z, f0.z);

    float a[16], h[16];

    // ---------------- ET MLP: x = [ssnow, swat, temp] ----------------
    // All weight reads are thread-invariant -> scalar loads (SGPR operands).
    #pragma unroll
    for (int j = 0; j < 16; j++) a[j] = etb1[j];
    #pragma unroll
    for (int j = 0; j < 16; j++) a[j] = fmaf(ssnow, etW1[j], a[j]);
    #pragma unroll
    for (int j = 0; j < 16; j++) a[j] = fmaf(swat,  etW1[16 + j], a[j]);
    #pragma unroll
    for (int j = 0; j < 16; j++) a[j] = fmaf(temp,  etW1[32 + j], a[j]);
    #pragma unroll
    for (int j = 0; j < 16; j++) h[j] = fast_tanh(a[j]);

    #pragma unroll
    for (int j = 0; j < 16; j++) a[j] = etb2[j];
    #pragma unroll
    for (int k = 0; k < 16; k++) {
        float hk = h[k];
        #pragma unroll
        for (int j = 0; j < 16; j++)
            a[j] = fmaf(hk, etW2[k * 16 + j], a[j]);
    }
    #pragma unroll
    for (int j = 0; j < 16; j++) h[j] = fast_tanh(a[j]);

    float ET = etb3[0];
    #pragma unroll
    for (int j = 0; j < 16; j++) ET = fmaf(h[j], etW3[j], ET);

    // ---------------- Q MLP: x = [swat, precp] ----------------
    #pragma unroll
    for (int j = 0; j < 16; j++) a[j] = qb1[j];
    #pragma unroll
    for (int j = 0; j < 16; j++) a[j] = fmaf(swat,  qW1[j], a[j]);
    #pragma unroll
    for (int j = 0; j < 16; j++) a[j] = fmaf(precp, qW1[16 + j], a[j]);
    #pragma unroll
    for (int j = 0; j < 16; j++) h[j] = fast_tanh(a[j]);

    #pragma unroll
    for (int j = 0; j < 16; j++) a[j] = qb2[j];
    #pragma unroll
    for (int k = 0; k < 16; k++) {
        float hk = h[k];
        #pragma unroll
        for (int j = 0; j < 16; j++)
            a[j] = fmaf(hk, qW2[k * 16 + j], a[j]);
    }
    #pragma unroll
    for (int j = 0; j < 16; j++) h[j] = fast_tanh(a[j]);

    float Q = qb3[0];
    #pragma unroll
    for (int j = 0; j < 16; j++) Q = fmaf(h[j], qW3[j], Q);

    // ---------------- bucket physics ----------------
    float dT      = temp - Tmax;
    float melt    = stepf(dT) * stepf(ssnow) * fminf(ssnow, Df * dT);
    float st_snow = stepf(Tmin - temp);           // snowfall gate
    float Ps      = st_snow * precp;
    float Pr      = (1.0f - st_snow) * precp;     // step(temp-Tmin) == 1-step(Tmin-temp)
    float sw01    = stepf(swat);

    float dS1 = Ps - melt;
    float dS2 = Pr + melt - sw01 * (lday * __expf(ET) + __expf(Q));

    out[i]     = dS1;
    out[N + i] = dS2;
}

extern "C" void kernel_launch(void* const* d_in, const int* in_sizes, int n_in,
                              void* d_out, int out_size, void* d_ws, size_t ws_size,
                              hipStream_t stream) {
    const float* t        = (const float*)d_in[0];
    const float* S_snow   = (const float*)d_in[1];
    const float* S_water  = (const float*)d_in[2];
    // d_in[3] = ts (uniform grid 0..T-1, only need T)
    const float* precp_s  = (const float*)d_in[4];
    const float* temp_s   = (const float*)d_in[5];
    const float* lday_s   = (const float*)d_in[6];
    const float* etW1     = (const float*)d_in[7];
    const float* etb1     = (const float*)d_in[8];
    const float* etW2     = (const float*)d_in[9];
    const float* etb2     = (const float*)d_in[10];
    const float* etW3     = (const float*)d_in[11];
    const float* etb3     = (const float*)d_in[12];
    const float* qW1      = (const float*)d_in[13];
    const float* qb1      = (const float*)d_in[14];
    const float* qW2      = (const float*)d_in[15];
    const float* qb2      = (const float*)d_in[16];
    const float* qW3      = (const float*)d_in[17];
    const float* qb3      = (const float*)d_in[18];
    const float* pDf      = (const float*)d_in[19];
    const float* pTmax    = (const float*)d_in[20];
    const float* pTmin    = (const float*)d_in[21];

    int N = in_sizes[0];
    int T = in_sizes[3];
    float* out = (float*)d_out;
    float4* F = (float4*)d_ws;   // T*16 bytes = 160 KB, fits ws

    pack_forcings_kernel<<<(T + BLOCK - 1) / BLOCK, BLOCK, 0, stream>>>(
        precp_s, temp_s, lday_s, F, T);

    exphydro_rhs_kernel<<<(N + BLOCK - 1) / BLOCK, BLOCK, 0, stream>>>(
        t, S_snow, S_water, F,
        etW1, etb1, etW2, etb2, etW3, etb3,
        qW1, qb1, qW2, qb2, qW3, qb3,
        pDf, pTmax, pTmin, out, N, T);
}

// Round 3
// 49.311 us; speedup vs baseline: 3.7505x; 1.5123x over previous
//
#include <hip/hip_runtime.h>
#include <math.h>

#define BLOCK 256

typedef _Float16 half4v __attribute__((ext_vector_type(4)));
typedef float    float4v __attribute__((ext_vector_type(4)));

// tanh(x) = 1 - 2/(exp(2x)+1)  via v_exp_f32 + v_rcp_f32 (~1e-7 rel, saturates
// correctly for |x| large: exp->inf/0 handled by rcp)
__device__ __forceinline__ float fast_tanh(float x) {
    float e = __expf(2.0f * x);
    float r = __builtin_amdgcn_rcpf(e + 1.0f);
    return 1.0f - 2.0f * r;
}

__device__ __forceinline__ float stepf(float x) {
    return (fast_tanh(5.0f * x) + 1.0f) * 0.5f;
}

// Pack the 3 forcing series into an interleaved float4 table in d_ws.
__global__ __launch_bounds__(BLOCK) void pack_forcings_kernel(
    const float* __restrict__ precp_s, const float* __restrict__ temp_s,
    const float* __restrict__ lday_s, float4* __restrict__ F, int T)
{
    int i = blockIdx.x * BLOCK + threadIdx.x;
    if (i < T) F[i] = make_float4(precp_s[i], temp_s[i], lday_s[i], 0.0f);
}

// MFMA 16x16x16 f16, swapped orientation: D = W^T · X  (cols = points).
// Fragment maps (verified family: C/D col=lane&15, row=4*(lane>>4)+reg):
//   A: lane holds A[m = lane&15][k = 4*(lane>>4)+j], j=0..3
//   B: lane holds B[k = 4*(lane>>4)+j][c = lane&15]
//   D: lane holds D[r = 4*(lane>>4)+reg][c = lane&15]
// => D's per-lane rows == next B's per-lane k's: layers chain shuffle-free.
__global__ __launch_bounds__(BLOCK, 4) void exphydro_mfma_kernel(
    const float* __restrict__ t, const float* __restrict__ S_snow,
    const float* __restrict__ S_water,
    const float4* __restrict__ F,
    const float* __restrict__ etW1, const float* __restrict__ etb1,
    const float* __restrict__ etW2, const float* __restrict__ etb2,
    const float* __restrict__ etW3, const float* __restrict__ etb3,
    const float* __restrict__ qW1, const float* __restrict__ qb1,
    const float* __restrict__ qW2, const float* __restrict__ qb2,
    const float* __restrict__ qW3, const float* __restrict__ qb3,
    const float* __restrict__ pDf, const float* __restrict__ pTmax,
    const float* __restrict__ pTmin,
    float* __restrict__ out, int N, int T)
{
    const int lane = threadIdx.x & 63;
    const int hi   = lane >> 4;        // 0..3 (k/row quadrant)
    const int m    = lane & 15;        // A-row / B-col / D-col index
    const int wave = threadIdx.x >> 6;
    const int base = blockIdx.x * BLOCK + wave * 64;   // this wave's 64 points
    const int p    = base + lane;
    const int pc   = (p < N) ? p : (N - 1);

    // ---------- A-fragments (weights, transposed), fp16; built per-thread ----------
    // Layer1: bias folded as extra input row (k==3 for ET, k==2 for Q).
    half4v A1et, A1q, A2et, A2q, A3et, A3q;
    float4v C2et, C2q;
    #pragma unroll
    for (int j = 0; j < 4; j++) {
        int k = 4 * hi + j;
        float w1e = (k < 3) ? etW1[k * 16 + m] : ((k == 3) ? etb1[m] : 0.0f);
        float w1q = (k < 2) ? qW1 [k * 16 + m] : ((k == 2) ? qb1 [m] : 0.0f);
        A1et[j] = (_Float16)w1e;
        A1q [j] = (_Float16)w1q;
        A2et[j] = (_Float16)etW2[k * 16 + m];
        A2q [j] = (_Float16)qW2 [k * 16 + m];
        A3et[j] = (_Float16)((m == 0) ? etW3[k] : 0.0f);
        A3q [j] = (_Float16)((m == 0) ? qW3 [k] : 0.0f);
        C2et[j] = etb2[4 * hi + j];    // layer2 bias via C operand (row=4*hi+reg)
        C2q [j] = qb2 [4 * hi + j];
    }

    const float Df   = pDf[0];
    const float Tmax = pTmax[0];
    const float Tmin = pTmin[0];
    const float b3et = etb3[0];
    const float b3q  = qb3[0];
    const float tmaxf = (float)(T - 1);
    const int   imax  = T - 2;

    // ---------- per-point loads + forcing interpolation (f32) ----------
    float tv    = t[pc];
    float ssnow = S_snow[pc];
    float swat  = S_water[pc];

    float tc = fminf(fmaxf(tv, 0.0f), tmaxf);
    int i0 = (int)tc;
    i0 = (i0 > imax) ? imax : i0;
    float fr = tc - (float)i0;
    float4 f0 = F[i0];
    float4 f1 = F[i0 + 1];
    float precp = fmaf(fr, f1.x - f0.x, f0.x);
    float temp  = fmaf(fr, f1.y - f0.y, f0.y);
    float lday  = fmaf(fr, f1.z - f0.z, f0.z);

    // ---------- MLPs via chained MFMA, 4 groups of 16 points ----------
    const float4v zero4 = {0.0f, 0.0f, 0.0f, 0.0f};
    float et4[4], q4[4];

    #pragma unroll
    for (int g = 0; g < 4; g++) {
        const int src = (g << 4) | m;          // owner lane of this column's point
        float ss = __shfl(ssnow, src, 64);
        float sw = __shfl(swat,  src, 64);
        float tp = __shfl(temp,  src, 64);
        float pr = __shfl(precp, src, 64);

        // B1 frags: real inputs live at k=0..3 (ET) / k=0..2 (Q); lanes with
        // hi!=0 hold pad-k rows whose A columns are zero -> contribute nothing.
        half4v B1et, B1q;
        B1et[0] = (_Float16)ss;  B1et[1] = (_Float16)sw;
        B1et[2] = (_Float16)tp;  B1et[3] = (_Float16)1.0f;
        B1q [0] = (_Float16)sw;  B1q [1] = (_Float16)pr;
        B1q [2] = (_Float16)1.0f; B1q[3] = (_Float16)0.0f;

        float4v d1e = __builtin_amdgcn_mfma_f32_16x16x16f16(A1et, B1et, zero4, 0, 0, 0);
        float4v d1q = __builtin_amdgcn_mfma_f32_16x16x16f16(A1q,  B1q,  zero4, 0, 0, 0);

        half4v B2et, B2q;
        #pragma unroll
        for (int r = 0; r < 4; r++) B2et[r] = (_Float16)fast_tanh(d1e[r]);
        #pragma unroll
        for (int r = 0; r < 4; r++) B2q [r] = (_Float16)fast_tanh(d1q[r]);

        float4v d2e = __builtin_amdgcn_mfma_f32_16x16x16f16(A2et, B2et, C2et, 0, 0, 0);
        float4v d2q = __builtin_amdgcn_mfma_f32_16x16x16f16(A2q,  B2q,  C2q,  0, 0, 0);

        half4v B3et, B3q;
        #pragma unroll
        for (int r = 0; r < 4; r++) B3et[r] = (_Float16)fast_tanh(d2e[r]);
        #pragma unroll
        for (int r = 0; r < 4; r++) B3q [r] = (_Float16)fast_tanh(d2q[r]);

        float4v d3e = __builtin_amdgcn_mfma_f32_16x16x16f16(A3et, B3et, zero4, 0, 0, 0);
        float4v d3q = __builtin_amdgcn_mfma_f32_16x16x16f16(A3q,  B3q,  zero4, 0, 0, 0);

        et4[g] = d3e[0];   // row0 (=ET of point (g,m)) valid in lanes hi==0
        q4 [g] = d3q[0];
    }

    // ---------- distribute ET/Q back to owner lane (point = lane) ----------
    float e0 = __shfl(et4[0], m, 64);
    float e1 = __shfl(et4[1], m, 64);
    float e2 = __shfl(et4[2], m, 64);
    float e3 = __shfl(et4[3], m, 64);
    float q0 = __shfl(q4[0], m, 64);
    float q1 = __shfl(q4[1], m, 64);
    float q2 = __shfl(q4[2], m, 64);
    float q3 = __shfl(q4[3], m, 64);
    float e01 = (lane & 16) ? e1 : e0;
    float e23 = (lane & 16) ? e3 : e2;
    float ET  = ((lane & 32) ? e23 : e01) + b3et;
    float q01 = (lane & 16) ? q1 : q0;
    float q23 = (lane & 16) ? q3 : q2;
    float Q   = ((lane & 32) ? q23 : q01) + b3q;

    // ---------- bucket physics ----------
    float dT      = temp - Tmax;
    float melt    = stepf(dT) * stepf(ssnow) * fminf(ssnow, Df * dT);
    float st_snow = stepf(Tmin - temp);
    float Ps      = st_snow * precp;
    float Pr      = (1.0f - st_snow) * precp;
    float sw01    = stepf(swat);

    float dS1 = Ps - melt;
    float dS2 = Pr + melt - sw01 * (lday * __expf(ET) + __expf(Q));

    if (p < N) {
        out[p]     = dS1;
        out[N + p] = dS2;
    }
}

extern "C" void kernel_launch(void* const* d_in, const int* in_sizes, int n_in,
                              void* d_out, int out_size, void* d_ws, size_t ws_size,
                              hipStream_t stream) {
    const float* t        = (const float*)d_in[0];
    const float* S_snow   = (const float*)d_in[1];
    const float* S_water  = (const float*)d_in[2];
    const float* precp_s  = (const float*)d_in[4];
    const float* temp_s   = (const float*)d_in[5];
    const float* lday_s   = (const float*)d_in[6];
    const float* etW1     = (const float*)d_in[7];
    const float* etb1     = (const float*)d_in[8];
    const float* etW2     = (const float*)d_in[9];
    const float* etb2     = (const float*)d_in[10];
    const float* etW3     = (const float*)d_in[11];
    const float* etb3     = (const float*)d_in[12];
    const float* qW1      = (const float*)d_in[13];
    const float* qb1      = (const float*)d_in[14];
    const float* qW2      = (const float*)d_in[15];
    const float* qb2      = (const float*)d_in[16];
    const float* qW3      = (const float*)d_in[17];
    const float* qb3      = (const float*)d_in[18];
    const float* pDf      = (const float*)d_in[19];
    const float* pTmax    = (const float*)d_in[20];
    const float* pTmin    = (const float*)d_in[21];

    int N = in_sizes[0];
    int T = in_sizes[3];
    float* out = (float*)d_out;
    float4* F = (float4*)d_ws;   // T*16 bytes, fits ws (worked in round 2)

    pack_forcings_kernel<<<(T + BLOCK - 1) / BLOCK, BLOCK, 0, stream>>>(
        precp_s, temp_s, lday_s, F, T);

    exphydro_mfma_kernel<<<(N + BLOCK - 1) / BLOCK, BLOCK, 0, stream>>>(
        t, S_snow, S_water, F,
        etW1, etb1, etW2, etb2, etW3, etb3,
        qW1, qb1, qW2, qb2, qW3, qb3,
        pDf, pTmax, pTmin, out, N, T);
}

// Round 5
// 42.636 us; speedup vs baseline: 4.3377x; 1.1565x over previous
//
#include <hip/hip_runtime.h>
#include <math.h>

#define BLOCK 256

typedef _Float16 half2v __attribute__((ext_vector_type(2)));
typedef _Float16 half4v __attribute__((ext_vector_type(4)));
typedef float    float4v __attribute__((ext_vector_type(4)));

__device__ __forceinline__ half2v cvt_pk_h2(float a, float b) {
    return __builtin_bit_cast(half2v, __builtin_amdgcn_cvt_pkrtz(a, b));
}

#define H4(x) {(_Float16)(x), (_Float16)(x), (_Float16)(x), (_Float16)(x)}

// Packed-fp16 tanh: odd poly t*p(t^2), deg-5 in s, Chebyshev-fit on s in [0,9],
// clamp |x|<=3. Endpoint lifted so 3*p(9) == 1.0: saturated units (the common
// case here: pre-acts up to ~1000) produce exactly +-1.0, no systematic bias.
// In-band abs err ~5e-3 (fit) + ~3e-3 (fp16 Horner).
__device__ __forceinline__ half4v tanh_pk4(half4v x) {
    const half4v c5 = H4(-3.71625e-05f);
    const half4v c4 = H4( 1.09648e-03f);
    const half4v c3 = H4(-1.288264e-02f);
    const half4v c2 = H4( 7.941906e-02f);
    const half4v c1 = H4(-3.0042735e-01f);
    const half4v c0 = H4( 9.9607644e-01f);
    const half4v hi = H4( 3.0f);
    const half4v lo = H4(-3.0f);
    half4v t = __builtin_elementwise_min(__builtin_elementwise_max(x, lo), hi);
    half4v s = t * t;
#if __has_builtin(__builtin_elementwise_fma)
    half4v p = __builtin_elementwise_fma(c5, s, c4);
    p = __builtin_elementwise_fma(p, s, c3);
    p = __builtin_elementwise_fma(p, s, c2);
    p = __builtin_elementwise_fma(p, s, c1);
    p = __builtin_elementwise_fma(p, s, c0);
#else
    half4v p = c5 * s + c4;
    p = p * s + c3;
    p = p * s + c2;
    p = p * s + c1;
    p = p * s + c0;
#endif
    return t * p;
}

__device__ __forceinline__ half4v pk4_from_f32(float a, float b, float c, float d) {
    half2v lo = cvt_pk_h2(a, b);
    half2v hi = cvt_pk_h2(c, d);
    return __builtin_shufflevector(lo, hi, 0, 1, 2, 3);
}

__device__ __forceinline__ half4v act4(float4v d) {
    return tanh_pk4(pk4_from_f32(d[0], d[1], d[2], d[3]));
}

// Pack the 3 forcing series into an interleaved float4 table in d_ws.
__global__ __launch_bounds__(BLOCK) void pack_forcings_kernel(
    const float* __restrict__ precp_s, const float* __restrict__ temp_s,
    const float* __restrict__ lday_s, float4* __restrict__ F, int T)
{
    int i = blockIdx.x * BLOCK + threadIdx.x;
    if (i < T) F[i] = make_float4(precp_s[i], temp_s[i], lday_s[i], 0.0f);
}

// MFMA 16x16x16 f16, swapped orientation: D = W^T . X  (cols = points).
//   A: lane holds A[m = lane&15][k = 4*(lane>>4)+j]
//   B: lane holds B[k = 4*(lane>>4)+j][c = lane&15]
//   D: lane holds D[r = 4*(lane>>4)+reg][c = lane&15]
// D rows == next B's k's -> layers chain shuffle-free. Layer-3 weight rows are
// REPLICATED across all 16 rows, so every lane's d3[0] = out(col) and the
// owner-lane pickup is a 3-cndmask select (no shfl).
__global__ __launch_bounds__(BLOCK, 4) void exphydro_mfma_kernel(
    const float* __restrict__ t, const float* __restrict__ S_snow,
    const float* __restrict__ S_water,
    const float4* __restrict__ F,
    const float* __restrict__ etW1, const float* __restrict__ etb1,
    const float* __restrict__ etW2, const float* __restrict__ etb2,
    const float* __restrict__ etW3, const float* __restrict__ etb3,
    const float* __restrict__ qW1, const float* __restrict__ qb1,
    const float* __restrict__ qW2, const float* __restrict__ qb2,
    const float* __restrict__ qW3, const float* __restrict__ qb3,
    const float* __restrict__ pDf, const float* __restrict__ pTmax,
    const float* __restrict__ pTmin,
    float* __restrict__ out, int N, int T)
{
    const int lane = threadIdx.x & 63;
    const int hi   = lane >> 4;        // 0..3 (k/row quadrant)
    const int m    = lane & 15;        // A-row / B-col / D-col index
    const int wave = threadIdx.x >> 6;
    const int base = blockIdx.x * BLOCK + wave * 64;
    const int p    = base + lane;
    const int pc   = (p < N) ? p : (N - 1);

    // ---------- A-fragments (weights, transposed), fp16 ----------
    half4v A1et, A1q, A2et, A2q, A3et, A3q;
    float4v C2et, C2q, C3et, C3q;
    #pragma unroll
    for (int j = 0; j < 4; j++) {
        int k = 4 * hi + j;
        float w1e = (k < 3) ? etW1[k * 16 + m] : ((k == 3) ? etb1[m] : 0.0f);
        float w1q = (k < 2) ? qW1 [k * 16 + m] : ((k == 2) ? qb1 [m] : 0.0f);
        A1et[j] = (_Float16)w1e;
        A1q [j] = (_Float16)w1q;
        A2et[j] = (_Float16)etW2[k * 16 + m];
        A2q [j] = (_Float16)qW2 [k * 16 + m];
        A3et[j] = (_Float16)etW3[k];     // replicated over all rows m
        A3q [j] = (_Float16)qW3 [k];
        C2et[j] = etb2[4 * hi + j];
        C2q [j] = qb2 [4 * hi + j];
        C3et[j] = etb3[0];
        C3q [j] = qb3 [0];
    }

    const float Df   = pDf[0];
    const float Tmax = pTmax[0];
    const float Tmin = pTmin[0];
    const float tmaxf = (float)(T - 1);
    const int   imax  = T - 2;

    // ---------- per-point loads + forcing interpolation (f32) ----------
    float tv    = t[pc];
    float ssnow = S_snow[pc];
    float swat  = S_water[pc];

    float tc = fminf(fmaxf(tv, 0.0f), tmaxf);
    int i0 = (int)tc;
    i0 = (i0 > imax) ? imax : i0;
    float fr = tc - (float)i0;
    float4 f0 = F[i0];
    float4 f1 = F[i0 + 1];
    float precp = fmaf(fr, f1.x - f0.x, f0.x);
    float temp  = fmaf(fr, f1.y - f0.y, f0.y);
    float lday  = fmaf(fr, f1.z - f0.z, f0.z);

    // pack this point's MLP inputs for cheap cross-lane distribution
    half2v my01 = cvt_pk_h2(ssnow, swat);
    half2v my23 = cvt_pk_h2(temp, precp);
    int i01 = __builtin_bit_cast(int, my01);
    int i23 = __builtin_bit_cast(int, my23);

    // ---------- MLPs via chained MFMA, 4 groups of 16 points ----------
    const float4v zero4 = {0.0f, 0.0f, 0.0f, 0.0f};
    const _Float16 oneh = (_Float16)1.0f;
    const _Float16 zerh = (_Float16)0.0f;
    float et0, et1, et2, et3, q0, q1, q2, q3;

    #pragma unroll
    for (int g = 0; g < 4; g++) {
        const int src = (g << 4) | m;
        int j01 = __shfl(i01, src, 64);
        int j23 = __shfl(i23, src, 64);
        half2v a01 = __builtin_bit_cast(half2v, j01);   // (ssnow, swat)
        half2v a23 = __builtin_bit_cast(half2v, j23);   // (temp, precp)

        half4v B1et = {a01[0], a01[1], a23[0], oneh};   // ss, sw, tp, 1
        half4v B1q  = {a01[1], a23[1], oneh,  zerh};    // sw, pr, 1, 0

        float4v d1e = __builtin_amdgcn_mfma_f32_16x16x16f16(A1et, B1et, zero4, 0, 0, 0);
        float4v d1q = __builtin_amdgcn_mfma_f32_16x16x16f16(A1q,  B1q,  zero4, 0, 0, 0);

        half4v B2et = act4(d1e);
        half4v B2q  = act4(d1q);

        float4v d2e = __builtin_amdgcn_mfma_f32_16x16x16f16(A2et, B2et, C2et, 0, 0, 0);
        float4v d2q = __builtin_amdgcn_mfma_f32_16x16x16f16(A2q,  B2q,  C2q,  0, 0, 0);

        half4v B3et = act4(d2e);
        half4v B3q  = act4(d2q);

        float4v d3e = __builtin_amdgcn_mfma_f32_16x16x16f16(A3et, B3et, C3et, 0, 0, 0);
        float4v d3q = __builtin_amdgcn_mfma_f32_16x16x16f16(A3q,  B3q,  C3q,  0, 0, 0);

        if (g == 0) { et0 = d3e[0]; q0 = d3q[0]; }
        if (g == 1) { et1 = d3e[0]; q1 = d3q[0]; }
        if (g == 2) { et2 = d3e[0]; q2 = d3q[0]; }
        if (g == 3) { et3 = d3e[0]; q3 = d3q[0]; }
    }

    // owner-lane pickup: point p = base + lane lives in group (lane>>4), col m
    float e01 = (lane & 16) ? et1 : et0;
    float e23 = (lane & 16) ? et3 : et2;
    float ET  = (lane & 32) ? e23 : e01;
    float q01 = (lane & 16) ? q1 : q0;
    float q23 = (lane & 16) ? q3 : q2;
    float Q   = (lane & 32) ? q23 : q01;

    // ---------- bucket physics (steps via the same packed poly) ----------
    float dT = temp - Tmax;
    half4v sargs = pk4_from_f32(5.0f * dT, 5.0f * ssnow,
                                5.0f * (Tmin - temp), 5.0f * swat);
    half4v th = tanh_pk4(sargs);
    float stepA  = fmaf(0.5f, (float)th[0], 0.5f);   // step(temp - Tmax)
    float stepSn = fmaf(0.5f, (float)th[1], 0.5f);   // step(S_snow)
    float stepPs = fmaf(0.5f, (float)th[2], 0.5f);   // step(Tmin - temp)
    float sw01   = fmaf(0.5f, (float)th[3], 0.5f);   // step(S_water)

    float melt = stepA * stepSn * fminf(ssnow, Df * dT);
    float Ps   = stepPs * precp;
    float Pr   = (1.0f - stepPs) * precp;

    float dS1 = Ps - melt;
    float dS2 = Pr + melt - sw01 * (lday * __expf(ET) + __expf(Q));

    if (p < N) {
        out[p]     = dS1;
        out[N + p] = dS2;
    }
}

extern "C" void kernel_launch(void* const* d_in, const int* in_sizes, int n_in,
                              void* d_out, int out_size, void* d_ws, size_t ws_size,
                              hipStream_t stream) {
    const float* t        = (const float*)d_in[0];
    const float* S_snow   = (const float*)d_in[1];
    const float* S_water  = (const float*)d_in[2];
    const float* precp_s  = (const float*)d_in[4];
    const float* temp_s   = (const float*)d_in[5];
    const float* lday_s   = (const float*)d_in[6];
    const float* etW1     = (const float*)d_in[7];
    const float* etb1     = (const float*)d_in[8];
    const float* etW2     = (const float*)d_in[9];
    const float* etb2     = (const float*)d_in[10];
    const float* etW3     = (const float*)d_in[11];
    const float* etb3     = (const float*)d_in[12];
    const float* qW1      = (const float*)d_in[13];
    const float* qb1      = (const float*)d_in[14];
    const float* qW2      = (const float*)d_in[15];
    const float* qb2      = (const float*)d_in[16];
    const float* qW3      = (const float*)d_in[17];
    const float* qb3      = (const float*)d_in[18];
    const float* pDf      = (const float*)d_in[19];
    const float* pTmax    = (const float*)d_in[20];
    const float* pTmin    = (const float*)d_in[21];

    int N = in_sizes[0];
    int T = in_sizes[3];
    float* out = (float*)d_out;
    float4* F = (float4*)d_ws;   // T*16 bytes, fits ws

    pack_forcings_kernel<<<(T + BLOCK - 1) / BLOCK, BLOCK, 0, stream>>>(
        precp_s, temp_s, lday_s, F, T);

    exphydro_mfma_kernel<<<(N + BLOCK - 1) / BLOCK, BLOCK, 0, stream>>>(
        t, S_snow, S_water, F,
        etW1, etb1, etW2, etb2, etW3, etb3,
        qW1, qb1, qW2, qb2, qW3, qb3,
        pDf, pTmax, pTmin, out, N, T);
}